// Round 1
// baseline (1886.560 us; speedup 1.0000x reference)
//
#include <hip/hip_runtime.h>

#define N_NODES 100000
#define N_EDGES 1600000
#define HID 128

typedef __attribute__((ext_vector_type(8))) short short8;
typedef __attribute__((ext_vector_type(4))) float float4v;
typedef __attribute__((ext_vector_type(2))) unsigned int uint2v;
typedef unsigned short ushort_t;
typedef unsigned int uint_t;

__device__ __forceinline__ float bits2f(uint_t u){ union{uint_t u; float f;} x; x.u=u; return x.f; }
__device__ __forceinline__ ushort_t f2b(float f){
  union{float f; uint_t u;} x; x.f=f;
  uint_t r = x.u + 0x7fffu + ((x.u>>16)&1u);
  return (ushort_t)(r>>16);
}
__device__ __forceinline__ float b2f(ushort_t u){ return bits2f(((uint_t)u)<<16); }
__device__ __forceinline__ float sigm(float x){ return 1.0f/(1.0f+__expf(-x)); }
__device__ __forceinline__ float tanh_f(float x){
  float t=__expf(-2.0f*fabsf(x)); float y=(1.0f-t)/(1.0f+t); return x>=0.f? y : -y;
}

// ---------------- preprocessing kernels ----------------

// Repack weights to bf16. WfT[o][t*128+d] = W_edge[t][o][d]; WihB/WhhB straight convert.
__global__ void prep_weights(const float* __restrict__ W_edge, const float* __restrict__ W_ih,
                             const float* __restrict__ W_hh, ushort_t* __restrict__ WfT,
                             ushort_t* __restrict__ WihB, ushort_t* __restrict__ WhhB){
  int i = blockIdx.x*256 + threadIdx.x;
  if (i < 65536){
    int o = i >> 9, k = i & 511, t = k >> 7, d = k & 127;
    WfT[i] = f2b(W_edge[t*16384 + o*128 + d]);
  } else if (i < 65536 + 49152){
    int j = i - 65536; WihB[j] = f2b(W_ih[j]);
  } else if (i < 65536 + 98304){
    int j = i - 65536 - 49152; WhhB[j] = f2b(W_hh[j]);
  }
}

// etype argmax, pack (t,src), histogram deg[dst] and cnt[dst][t]
__global__ void edge_pass1(const int* __restrict__ eidx, const float* __restrict__ efeat,
                           int* __restrict__ packed, int* __restrict__ deg, int* __restrict__ cnt){
  int e = blockIdx.x*256 + threadIdx.x;
  if (e >= N_EDGES) return;
  int src = eidx[e], dst = eidx[N_EDGES + e];
  float4v f = *(const float4v*)(efeat + (size_t)e*4);
  int t = 0; float b = f[0];
  if (f[1] > b){ b = f[1]; t = 1; }
  if (f[2] > b){ b = f[2]; t = 2; }
  if (f[3] > b){ b = f[3]; t = 3; }
  packed[e] = (t << 17) | src;
  atomicAdd(&deg[dst], 1);
  atomicAdd(&cnt[dst*4 + t], 1);
}

// single-block chunked exclusive scan (4 elems/thread), writes off[0..n] and cursor copy
__global__ void scan_kernel(const int* __restrict__ deg, int* __restrict__ off,
                            int* __restrict__ cur, int n){
  __shared__ int sh[1024];
  __shared__ int carry;
  int tid = threadIdx.x;
  if (tid == 0) carry = 0;
  __syncthreads();
  int nchunk = (n + 4095) / 4096;
  for (int c = 0; c < nchunk; ++c){
    int i0 = c*4096 + tid*4;
    int v0 = (i0+0<n)?deg[i0+0]:0;
    int v1 = (i0+1<n)?deg[i0+1]:0;
    int v2 = (i0+2<n)?deg[i0+2]:0;
    int v3 = (i0+3<n)?deg[i0+3]:0;
    int ts = v0+v1+v2+v3;
    sh[tid] = ts;
    __syncthreads();
    for (int d = 1; d < 1024; d <<= 1){
      int y = (tid >= d) ? sh[tid-d] : 0;
      __syncthreads();
      sh[tid] += y;
      __syncthreads();
    }
    int incl = sh[tid];
    int base = carry;
    int e0 = base + incl - ts;
    int e1 = e0+v0, e2 = e1+v1, e3 = e2+v2;
    if (i0+0<n){ off[i0+0]=e0; cur[i0+0]=e0; }
    if (i0+1<n){ off[i0+1]=e1; cur[i0+1]=e1; }
    if (i0+2<n){ off[i0+2]=e2; cur[i0+2]=e2; }
    if (i0+3<n){ off[i0+3]=e3; cur[i0+3]=e3; }
    __syncthreads();
    if (tid == 1023) carry = base + incl;
    __syncthreads();
  }
  if (tid == 0) off[n] = carry;
}

__global__ void edge_place(const int* __restrict__ eidx, const int* __restrict__ packed,
                           int* __restrict__ cur, int* __restrict__ sorted){
  int e = blockIdx.x*256 + threadIdx.x;
  if (e >= N_EDGES) return;
  int dst = eidx[N_EDGES + e];
  int p = atomicAdd(&cur[dst], 1);
  sorted[p] = packed[e];
}

// h(f32)=node_feat (into d_out), h_bf16 copy
__global__ void init_h(const float* __restrict__ nf, float* __restrict__ hF,
                       ushort_t* __restrict__ hB, int n4){
  int i = blockIdx.x*256 + threadIdx.x;
  if (i >= n4) return;
  float4v v = *(const float4v*)(nf + (size_t)i*4);
  *(float4v*)(hF + (size_t)i*4) = v;
  uint2v u;
  u[0] = (uint_t)f2b(v[0]) | ((uint_t)f2b(v[1])<<16);
  u[1] = (uint_t)f2b(v[2]) | ((uint_t)f2b(v[3])<<16);
  *(uint2v*)(hB + (size_t)i*4) = u;
}

// ---------------- per-step kernels ----------------

// one wave per node: s[v][t*128+d] = sum over incoming edges of type t of h_bf16[src][d]
__global__ void agg_kernel(const int* __restrict__ off, const int* __restrict__ sorted,
                           const ushort_t* __restrict__ hB, ushort_t* __restrict__ sB){
  int wid = (blockIdx.x * blockDim.x + threadIdx.x) >> 6;
  int lane = threadIdx.x & 63;
  if (wid >= N_NODES) return;
  int s = off[wid], e = off[wid+1];
  float a00=0,a01=0,a10=0,a11=0,a20=0,a21=0,a30=0,a31=0;
  int col = lane*2;
  for (int i = s; i < e; ++i){
    int p = sorted[i];
    int t = __builtin_amdgcn_readfirstlane(p >> 17);
    int src = p & 131071;
    uint_t hv = *(const uint_t*)(hB + (size_t)src*128 + col);
    float f0 = bits2f((hv & 0xffffu) << 16);
    float f1 = bits2f(hv & 0xffff0000u);
    if      (t == 0){ a00+=f0; a01+=f1; }
    else if (t == 1){ a10+=f0; a11+=f1; }
    else if (t == 2){ a20+=f0; a21+=f1; }
    else            { a30+=f0; a31+=f1; }
  }
  size_t o = (size_t)wid*512 + col;
  *(uint_t*)(sB + o + 0  ) = (uint_t)f2b(a00) | ((uint_t)f2b(a01)<<16);
  *(uint_t*)(sB + o + 128) = (uint_t)f2b(a10) | ((uint_t)f2b(a11)<<16);
  *(uint_t*)(sB + o + 256) = (uint_t)f2b(a20) | ((uint_t)f2b(a21)<<16);
  *(uint_t*)(sB + o + 384) = (uint_t)f2b(a30) | ((uint_t)f2b(a31)<<16);
}

// a_bf16 = s(Nx512) @ WfT^T(512x128) + sum_t cnt[v][t]*b_edge[t][:]
__launch_bounds__(256)
__global__ void gemm_a_kernel(const ushort_t* __restrict__ sB, const ushort_t* __restrict__ WfT,
                              const int* __restrict__ cnt, const float* __restrict__ b_edge,
                              ushort_t* __restrict__ aB){
  __shared__ ushort_t lA[128*64];
  __shared__ ushort_t lB[128*64];
  int tid = threadIdx.x;
  int w = tid >> 6, lane = tid & 63;
  int wm = w >> 1, wn = w & 1;
  int row0 = blockIdx.x * 128;
  float4v acc[4][4] = {};
  for (int kt = 0; kt < 8; ++kt){
    int k0 = kt * 64;
    #pragma unroll
    for (int i = 0; i < 4; ++i){
      int sgi = i*256 + tid;
      int r = sgi >> 3, kk = sgi & 7;
      int grow = row0 + r; if (grow >= N_NODES) grow = N_NODES-1;
      *reinterpret_cast<short8*>(lA + sgi*8) =
        *reinterpret_cast<const short8*>(sB + (size_t)grow*512 + k0 + kk*8);
    }
    #pragma unroll
    for (int i = 0; i < 4; ++i){
      int sgi = i*256 + tid;
      int r = sgi >> 3, kk = sgi & 7;
      *reinterpret_cast<short8*>(lB + sgi*8) =
        *reinterpret_cast<const short8*>(WfT + r*512 + k0 + kk*8);
    }
    __syncthreads();
    #pragma unroll
    for (int kk = 0; kk < 2; ++kk){
      int klo = kk*32 + (lane>>4)*8;
      short8 af[4], bf[4];
      #pragma unroll
      for (int i = 0; i < 4; ++i)
        af[i] = *reinterpret_cast<const short8*>(lA + (wm*64 + i*16 + (lane&15))*64 + klo);
      #pragma unroll
      for (int j = 0; j < 4; ++j)
        bf[j] = *reinterpret_cast<const short8*>(lB + (wn*64 + j*16 + (lane&15))*64 + klo);
      #pragma unroll
      for (int i = 0; i < 4; ++i)
        #pragma unroll
        for (int j = 0; j < 4; ++j)
          acc[i][j] = __builtin_amdgcn_mfma_f32_16x16x32_bf16(af[i], bf[j], acc[i][j], 0, 0, 0);
    }
    __syncthreads();
  }
  #pragma unroll
  for (int i = 0; i < 4; ++i){
    #pragma unroll
    for (int q = 0; q < 4; ++q){
      int grow = row0 + wm*64 + i*16 + (lane>>4)*4 + q;
      if (grow >= N_NODES) continue;
      const int* c4 = cnt + grow*4;
      float c0 = (float)c4[0], c1 = (float)c4[1], c2 = (float)c4[2], c3 = (float)c4[3];
      #pragma unroll
      for (int j = 0; j < 4; ++j){
        int colc = wn*64 + j*16 + (lane&15);
        float v = acc[i][j][q] + c0*b_edge[colc] + c1*b_edge[128+colc]
                               + c2*b_edge[256+colc] + c3*b_edge[384+colc];
        aB[(size_t)grow*128 + colc] = f2b(v);
      }
    }
  }
}

// fused GRU: gi = a@W_ih^T + b_ih ; gh = h@W_hh^T + b_hh ; gates ; h' -> hF(f32) & hB(bf16)
__launch_bounds__(512)
__global__ void gru_kernel(const ushort_t* __restrict__ aB, ushort_t* __restrict__ hB,
                           const ushort_t* __restrict__ WihB, const ushort_t* __restrict__ WhhB,
                           const float* __restrict__ b_ih, const float* __restrict__ b_hh,
                           float* __restrict__ hF){
  __shared__ float S[4][64][128];   // r, z, inn, hn  (128 KB)
  int tid = threadIdx.x, w = tid >> 6, lane = tid & 63;
  int wm = w >> 2, wn = w & 3;
  int row0 = blockIdx.x * 64;
  float4v ai[2][6] = {}, ah[2][6] = {};
  #pragma unroll
  for (int ks = 0; ks < 4; ++ks){
    int klo = ks*32 + (lane>>4)*8;
    short8 fa[2], fh[2];
    #pragma unroll
    for (int i = 0; i < 2; ++i){
      int grow = row0 + wm*32 + i*16 + (lane&15); if (grow >= N_NODES) grow = N_NODES-1;
      fa[i] = *reinterpret_cast<const short8*>(aB + (size_t)grow*128 + klo);
      fh[i] = *reinterpret_cast<const short8*>(hB + (size_t)grow*128 + klo);
    }
    #pragma unroll
    for (int j = 0; j < 6; ++j){
      int g = wn*96 + j*16 + (lane&15);
      short8 bi = *reinterpret_cast<const short8*>(WihB + g*128 + klo);
      short8 bh = *reinterpret_cast<const short8*>(WhhB + g*128 + klo);
      #pragma unroll
      for (int i = 0; i < 2; ++i){
        ai[i][j] = __builtin_amdgcn_mfma_f32_16x16x32_bf16(fa[i], bi, ai[i][j], 0, 0, 0);
        ah[i][j] = __builtin_amdgcn_mfma_f32_16x16x32_bf16(fh[i], bh, ah[i][j], 0, 0, 0);
      }
    }
  }
  // pass1: gi (+b_ih) into S[0..2]
  #pragma unroll
  for (int i = 0; i < 2; ++i)
    #pragma unroll
    for (int j = 0; j < 6; ++j)
      #pragma unroll
      for (int q = 0; q < 4; ++q){
        int rl = wm*32 + i*16 + (lane>>4)*4 + q;
        int colc = wn*96 + j*16 + (lane&15);
        S[colc>>7][rl][colc&127] = ai[i][j][q] + b_ih[colc];
      }
  __syncthreads();
  // pass2: gh (+b_hh): r/z chunks accumulate, n chunk goes to S[3]
  #pragma unroll
  for (int i = 0; i < 2; ++i)
    #pragma unroll
    for (int j = 0; j < 6; ++j)
      #pragma unroll
      for (int q = 0; q < 4; ++q){
        int rl = wm*32 + i*16 + (lane>>4)*4 + q;
        int colc = wn*96 + j*16 + (lane&15);
        float v = ah[i][j][q] + b_hh[colc];
        int ch = colc >> 7;
        if (ch < 2) S[ch][rl][colc&127] += v;
        else        S[3][rl][colc&127]  = v;
      }
  __syncthreads();
  for (int e = tid; e < 64*128; e += 512){
    int v = e >> 7, d = e & 127;
    int grow = row0 + v;
    if (grow >= N_NODES) continue;
    float r = sigm(S[0][v][d]);
    float z = sigm(S[1][v][d]);
    float n = tanh_f(S[2][v][d] + r*S[3][v][d]);
    float h = hF[(size_t)grow*128 + d];
    float hn = (1.0f - z)*n + z*h;
    hF[(size_t)grow*128 + d] = hn;
    hB[(size_t)grow*128 + d] = f2b(hn);
  }
}

// ---------------- launch ----------------

extern "C" void kernel_launch(void* const* d_in, const int* in_sizes, int n_in,
                              void* d_out, int out_size, void* d_ws, size_t ws_size,
                              hipStream_t stream) {
  const float* node_feat = (const float*)d_in[0];
  const int*   edge_idx  = (const int*)d_in[1];
  const float* edge_feat = (const float*)d_in[2];
  const float* W_edge    = (const float*)d_in[3];
  const float* b_edge    = (const float*)d_in[4];
  const float* W_ih      = (const float*)d_in[5];
  const float* W_hh      = (const float*)d_in[6];
  const float* b_ih      = (const float*)d_in[7];
  const float* b_hh      = (const float*)d_in[8];
  float* hF = (float*)d_out;

  char* p = (char*)d_ws;
  auto take = [&](size_t bytes) -> char* {
    char* r = p; p += (bytes + 255) & ~(size_t)255; return r;
  };
  ushort_t* WfT    = (ushort_t*)take(128*512*2);
  ushort_t* WihB   = (ushort_t*)take(384*128*2);
  ushort_t* WhhB   = (ushort_t*)take(384*128*2);
  int* deg    = (int*)take((size_t)N_NODES*4);
  int* cnt    = (int*)take((size_t)N_NODES*4*4);
  int* off    = (int*)take((size_t)(N_NODES+1)*4);
  int* cursor = (int*)take((size_t)N_NODES*4);
  int* packed = (int*)take((size_t)N_EDGES*4);
  int* sorted = (int*)take((size_t)N_EDGES*4);
  ushort_t* hB = (ushort_t*)take((size_t)N_NODES*128*2);
  ushort_t* sB = (ushort_t*)take((size_t)N_NODES*512*2);
  ushort_t* aB = (ushort_t*)take((size_t)N_NODES*128*2);

  hipMemsetAsync(deg, 0, (size_t)N_NODES*4, stream);
  hipMemsetAsync(cnt, 0, (size_t)N_NODES*16, stream);

  prep_weights<<<640, 256, 0, stream>>>(W_edge, W_ih, W_hh, WfT, WihB, WhhB);
  edge_pass1<<<(N_EDGES+255)/256, 256, 0, stream>>>(edge_idx, edge_feat, packed, deg, cnt);
  scan_kernel<<<1, 1024, 0, stream>>>(deg, off, cursor, N_NODES);
  edge_place<<<(N_EDGES+255)/256, 256, 0, stream>>>(edge_idx, packed, cursor, sorted);
  init_h<<<(N_NODES*32 + 255)/256, 256, 0, stream>>>(node_feat, hF, hB, N_NODES*32);

  for (int step = 0; step < 4; ++step){
    agg_kernel<<<(N_NODES+3)/4, 256, 0, stream>>>(off, sorted, hB, sB);
    gemm_a_kernel<<<(N_NODES+127)/128, 256, 0, stream>>>(sB, WfT, cnt, b_edge, aB);
    gru_kernel<<<(N_NODES+63)/64, 512, 0, stream>>>(aB, hB, WihB, WhhB, b_ih, b_hh, hF);
  }
}

// Round 2
// 1253.853 us; speedup vs baseline: 1.5046x; 1.5046x over previous
//
#include <hip/hip_runtime.h>

#define N_NODES 100000
#define N_EDGES 1600000
#define HID 128
#define SCAN_N (N_NODES*4)
#define NB ((SCAN_N + 1023) / 1024)

typedef __attribute__((ext_vector_type(8))) short short8;
typedef __attribute__((ext_vector_type(4))) float float4v;
typedef __attribute__((ext_vector_type(4))) int int4v;
typedef __attribute__((ext_vector_type(2))) unsigned int uint2v;
typedef unsigned short ushort_t;
typedef unsigned int uint_t;

__device__ __forceinline__ float bits2f(uint_t u){ union{uint_t u; float f;} x; x.u=u; return x.f; }
__device__ __forceinline__ ushort_t f2b(float f){
  union{float f; uint_t u;} x; x.f=f;
  uint_t r = x.u + 0x7fffu + ((x.u>>16)&1u);
  return (ushort_t)(r>>16);
}
__device__ __forceinline__ float sigm(float x){ return 1.0f/(1.0f+__expf(-x)); }
__device__ __forceinline__ float tanh_f(float x){
  float t=__expf(-2.0f*fabsf(x)); float y=(1.0f-t)/(1.0f+t); return x>=0.f? y : -y;
}

// ---------------- preprocessing ----------------

// Repack weights to bf16. WfT[o][t*128+d] = W_edge[t][o][d]; WihB/WhhB straight convert.
__global__ void prep_weights(const float* __restrict__ W_edge, const float* __restrict__ W_ih,
                             const float* __restrict__ W_hh, ushort_t* __restrict__ WfT,
                             ushort_t* __restrict__ WihB, ushort_t* __restrict__ WhhB){
  int i = blockIdx.x*256 + threadIdx.x;
  if (i < 65536){
    int o = i >> 9, k = i & 511, t = k >> 7, d = k & 127;
    WfT[i] = f2b(W_edge[t*16384 + o*128 + d]);
  } else if (i < 65536 + 49152){
    int j = i - 65536; WihB[j] = f2b(W_ih[j]);
  } else if (i < 65536 + 98304){
    int j = i - 65536 - 49152; WhhB[j] = f2b(W_hh[j]);
  }
}

// etype argmax, pack (t,src), histogram cnt[dst*4+t]
__global__ void edge_pass1(const int* __restrict__ eidx, const float* __restrict__ efeat,
                           int* __restrict__ packed, int* __restrict__ cnt){
  int e = blockIdx.x*256 + threadIdx.x;
  if (e >= N_EDGES) return;
  int src = eidx[e], dst = eidx[N_EDGES + e];
  float4v f = *(const float4v*)(efeat + (size_t)e*4);
  int t = 0; float b = f[0];
  if (f[1] > b){ b = f[1]; t = 1; }
  if (f[2] > b){ b = f[2]; t = 2; }
  if (f[3] > b){ b = f[3]; t = 3; }
  packed[e] = (t << 17) | src;
  atomicAdd(&cnt[dst*4 + t], 1);
}

// 3-pass exclusive scan over cnt[SCAN_N] -> off4, cursor copy
__global__ void scan_pass1(const int* __restrict__ cnt, int* __restrict__ bsum){
  __shared__ int ws[4];
  int tid = threadIdx.x, lane = tid & 63, w = tid >> 6;
  int idx = blockIdx.x*1024 + tid*4;
  int v = 0;
  if (idx + 3 < SCAN_N){ int4v x = *(const int4v*)(cnt + idx); v = x[0]+x[1]+x[2]+x[3]; }
  else { for (int k = 0; k < 4; ++k) if (idx + k < SCAN_N) v += cnt[idx+k]; }
  for (int d = 32; d; d >>= 1) v += __shfl_down(v, d);
  if (lane == 0) ws[w] = v;
  __syncthreads();
  if (tid == 0) bsum[blockIdx.x] = ws[0]+ws[1]+ws[2]+ws[3];
}

__global__ void scan_pass2(const int* __restrict__ bsum, int* __restrict__ bpre,
                           int* __restrict__ off4_last, int nb){
  __shared__ int sh[512];
  int tid = threadIdx.x;
  int v = (tid < nb) ? bsum[tid] : 0;
  sh[tid] = v;
  __syncthreads();
  for (int d = 1; d < 512; d <<= 1){
    int y = (tid >= d) ? sh[tid-d] : 0;
    __syncthreads();
    sh[tid] += y;
    __syncthreads();
  }
  if (tid < nb) bpre[tid] = sh[tid] - v;
  if (tid == 511) *off4_last = sh[511];
}

__global__ void scan_pass3(const int* __restrict__ cnt, const int* __restrict__ bpre,
                           int* __restrict__ off4, int* __restrict__ cur){
  __shared__ int wsum[4];
  int tid = threadIdx.x, lane = tid & 63, w = tid >> 6;
  int idx = blockIdx.x*1024 + tid*4;
  int v0=0,v1=0,v2=0,v3=0;
  if (idx + 3 < SCAN_N){ int4v x = *(const int4v*)(cnt + idx); v0=x[0];v1=x[1];v2=x[2];v3=x[3]; }
  else {
    if (idx   < SCAN_N) v0 = cnt[idx];
    if (idx+1 < SCAN_N) v1 = cnt[idx+1];
    if (idx+2 < SCAN_N) v2 = cnt[idx+2];
    if (idx+3 < SCAN_N) v3 = cnt[idx+3];
  }
  int ts = v0+v1+v2+v3;
  int sc = ts;
  for (int d = 1; d < 64; d <<= 1){ int y = __shfl_up(sc, d); if (lane >= d) sc += y; }
  if (lane == 63) wsum[w] = sc;
  __syncthreads();
  int wofs = 0;
  for (int k = 0; k < w; ++k) wofs += wsum[k];
  int base = bpre[blockIdx.x] + wofs + sc - ts;
  int e0 = base, e1 = e0+v0, e2 = e1+v1, e3 = e2+v2;
  if (idx   < SCAN_N){ off4[idx  ] = e0; cur[idx  ] = e0; }
  if (idx+1 < SCAN_N){ off4[idx+1] = e1; cur[idx+1] = e1; }
  if (idx+2 < SCAN_N){ off4[idx+2] = e2; cur[idx+2] = e2; }
  if (idx+3 < SCAN_N){ off4[idx+3] = e3; cur[idx+3] = e3; }
}

__global__ void edge_place(const int* __restrict__ eidx, const int* __restrict__ packed,
                           int* __restrict__ cur, int* __restrict__ sorted){
  int e = blockIdx.x*256 + threadIdx.x;
  if (e >= N_EDGES) return;
  int dst = eidx[N_EDGES + e];
  int p = packed[e];
  int t = p >> 17, src = p & 131071;
  int pos = atomicAdd(&cur[dst*4 + t], 1);
  sorted[pos] = src;
}

// h(f32)=node_feat (into d_out), h_bf16 copy
__global__ void init_h(const float* __restrict__ nf, float* __restrict__ hF,
                       ushort_t* __restrict__ hB, int n4){
  int i = blockIdx.x*256 + threadIdx.x;
  if (i >= n4) return;
  float4v v = *(const float4v*)(nf + (size_t)i*4);
  *(float4v*)(hF + (size_t)i*4) = v;
  uint2v u;
  u[0] = (uint_t)f2b(v[0]) | ((uint_t)f2b(v[1])<<16);
  u[1] = (uint_t)f2b(v[2]) | ((uint_t)f2b(v[3])<<16);
  *(uint2v*)(hB + (size_t)i*4) = u;
}

// ---------------- per-step kernels ----------------

// one wave per node; edges sorted by (dst, etype) -> 4 clean segments, unroll-4 gathers
__global__ void agg_kernel(const int* __restrict__ off4, const int* __restrict__ sorted,
                           const ushort_t* __restrict__ hB, ushort_t* __restrict__ sB){
  int wid = __builtin_amdgcn_readfirstlane((int)((blockIdx.x * blockDim.x + threadIdx.x) >> 6));
  int lane = threadIdx.x & 63;
  if (wid >= N_NODES) return;
  int col = lane*2;
  const int* o = off4 + wid*4;
  size_t outb = (size_t)wid*512 + (size_t)col;
  #pragma unroll
  for (int t = 0; t < 4; ++t){
    int s = o[t], e = o[t+1];
    float a0=0,a1=0,b0=0,b1=0,c0=0,c1=0,d0=0,d1=0;
    int i = s;
    for (; i + 4 <= e; i += 4){
      int s0 = sorted[i], s1 = sorted[i+1], s2 = sorted[i+2], s3 = sorted[i+3];
      uint_t h0 = *(const uint_t*)(hB + (size_t)s0*128 + col);
      uint_t h1 = *(const uint_t*)(hB + (size_t)s1*128 + col);
      uint_t h2 = *(const uint_t*)(hB + (size_t)s2*128 + col);
      uint_t h3 = *(const uint_t*)(hB + (size_t)s3*128 + col);
      a0 += bits2f((h0 & 0xffffu) << 16); a1 += bits2f(h0 & 0xffff0000u);
      b0 += bits2f((h1 & 0xffffu) << 16); b1 += bits2f(h1 & 0xffff0000u);
      c0 += bits2f((h2 & 0xffffu) << 16); c1 += bits2f(h2 & 0xffff0000u);
      d0 += bits2f((h3 & 0xffffu) << 16); d1 += bits2f(h3 & 0xffff0000u);
    }
    for (; i < e; ++i){
      int sv = sorted[i];
      uint_t hv = *(const uint_t*)(hB + (size_t)sv*128 + col);
      a0 += bits2f((hv & 0xffffu) << 16); a1 += bits2f(hv & 0xffff0000u);
    }
    float f0 = (a0+b0)+(c0+d0), f1 = (a1+b1)+(c1+d1);
    *(uint_t*)(sB + outb + t*128) = (uint_t)f2b(f0) | ((uint_t)f2b(f1) << 16);
  }
}

// a_bf16 = s(Nx512) @ WfT^T(512x128) + sum_t cnt[v][t]*b_edge[t][:]
__launch_bounds__(256)
__global__ void gemm_a_kernel(const ushort_t* __restrict__ sB, const ushort_t* __restrict__ WfT,
                              const int* __restrict__ cnt, const float* __restrict__ b_edge,
                              ushort_t* __restrict__ aB){
  __shared__ ushort_t lA[128*64];
  __shared__ ushort_t lB[128*64];
  int tid = threadIdx.x;
  int w = tid >> 6, lane = tid & 63;
  int wm = w >> 1, wn = w & 1;
  int row0 = blockIdx.x * 128;
  float4v acc[4][4] = {};
  for (int kt = 0; kt < 8; ++kt){
    int k0 = kt * 64;
    #pragma unroll
    for (int i = 0; i < 4; ++i){
      int sgi = i*256 + tid;
      int r = sgi >> 3, kk = sgi & 7;
      int grow = row0 + r; if (grow >= N_NODES) grow = N_NODES-1;
      *reinterpret_cast<short8*>(lA + sgi*8) =
        *reinterpret_cast<const short8*>(sB + (size_t)grow*512 + k0 + kk*8);
    }
    #pragma unroll
    for (int i = 0; i < 4; ++i){
      int sgi = i*256 + tid;
      int r = sgi >> 3, kk = sgi & 7;
      *reinterpret_cast<short8*>(lB + sgi*8) =
        *reinterpret_cast<const short8*>(WfT + r*512 + k0 + kk*8);
    }
    __syncthreads();
    #pragma unroll
    for (int kk = 0; kk < 2; ++kk){
      int klo = kk*32 + (lane>>4)*8;
      short8 af[4], bf[4];
      #pragma unroll
      for (int i = 0; i < 4; ++i)
        af[i] = *reinterpret_cast<const short8*>(lA + (wm*64 + i*16 + (lane&15))*64 + klo);
      #pragma unroll
      for (int j = 0; j < 4; ++j)
        bf[j] = *reinterpret_cast<const short8*>(lB + (wn*64 + j*16 + (lane&15))*64 + klo);
      #pragma unroll
      for (int i = 0; i < 4; ++i)
        #pragma unroll
        for (int j = 0; j < 4; ++j)
          acc[i][j] = __builtin_amdgcn_mfma_f32_16x16x32_bf16(af[i], bf[j], acc[i][j], 0, 0, 0);
    }
    __syncthreads();
  }
  #pragma unroll
  for (int i = 0; i < 4; ++i){
    #pragma unroll
    for (int q = 0; q < 4; ++q){
      int grow = row0 + wm*64 + i*16 + (lane>>4)*4 + q;
      if (grow >= N_NODES) continue;
      const int* c4 = cnt + grow*4;
      float c0 = (float)c4[0], c1 = (float)c4[1], c2 = (float)c4[2], c3 = (float)c4[3];
      #pragma unroll
      for (int j = 0; j < 4; ++j){
        int colc = wn*64 + j*16 + (lane&15);
        float v = acc[i][j][q] + c0*b_edge[colc] + c1*b_edge[128+colc]
                               + c2*b_edge[256+colc] + c3*b_edge[384+colc];
        aB[(size_t)grow*128 + colc] = f2b(v);
      }
    }
  }
}

// fused GRU, LDS-free: each wave owns 32 cols, computes r/z/n gates for those cols
// g2 = gate*2+jj ; weight row g = gate*128 + wn*32 + jj*16 + (lane&15)
__launch_bounds__(512)
__global__ void gru_kernel(const ushort_t* __restrict__ aB, ushort_t* __restrict__ hB,
                           const ushort_t* __restrict__ WihB, const ushort_t* __restrict__ WhhB,
                           const float* __restrict__ b_ih, const float* __restrict__ b_hh,
                           float* __restrict__ hF){
  int tid = threadIdx.x, w = tid >> 6, lane = tid & 63;
  int wm = w >> 2, wn = w & 3;
  int row0 = blockIdx.x * 64;
  float4v ai[2][6] = {}, ah[2][6] = {};
  #pragma unroll
  for (int ks = 0; ks < 4; ++ks){
    int klo = ks*32 + (lane>>4)*8;
    short8 fa[2], fh[2];
    #pragma unroll
    for (int i = 0; i < 2; ++i){
      int grow = row0 + wm*32 + i*16 + (lane&15); if (grow >= N_NODES) grow = N_NODES-1;
      fa[i] = *reinterpret_cast<const short8*>(aB + (size_t)grow*128 + klo);
      fh[i] = *reinterpret_cast<const short8*>(hB + (size_t)grow*128 + klo);
    }
    #pragma unroll
    for (int g2 = 0; g2 < 6; ++g2){
      int gate = g2 >> 1, jj = g2 & 1;
      int g = gate*128 + wn*32 + jj*16 + (lane&15);
      short8 bi = *reinterpret_cast<const short8*>(WihB + g*128 + klo);
      short8 bh = *reinterpret_cast<const short8*>(WhhB + g*128 + klo);
      #pragma unroll
      for (int i = 0; i < 2; ++i){
        ai[i][g2] = __builtin_amdgcn_mfma_f32_16x16x32_bf16(fa[i], bi, ai[i][g2], 0, 0, 0);
        ah[i][g2] = __builtin_amdgcn_mfma_f32_16x16x32_bf16(fh[i], bh, ah[i][g2], 0, 0, 0);
      }
    }
  }
  #pragma unroll
  for (int i = 0; i < 2; ++i){
    #pragma unroll
    for (int jj = 0; jj < 2; ++jj){
      int c = wn*32 + jj*16 + (lane&15);
      float bir = b_ih[c], biz = b_ih[128+c], bin = b_ih[256+c];
      float bhr = b_hh[c], bhz = b_hh[128+c], bhn = b_hh[256+c];
      #pragma unroll
      for (int q = 0; q < 4; ++q){
        int rrow = row0 + wm*32 + i*16 + (lane>>4)*4 + q;
        if (rrow >= N_NODES) continue;
        float r = sigm(ai[i][0+jj][q] + bir + ah[i][0+jj][q] + bhr);
        float z = sigm(ai[i][2+jj][q] + biz + ah[i][2+jj][q] + bhz);
        float hn = ah[i][4+jj][q] + bhn;
        float n = tanh_f(ai[i][4+jj][q] + bin + r*hn);
        float h = hF[(size_t)rrow*128 + c];
        float out = (1.0f - z)*n + z*h;
        hF[(size_t)rrow*128 + c] = out;
        hB[(size_t)rrow*128 + c] = f2b(out);
      }
    }
  }
}

// ---------------- launch ----------------

extern "C" void kernel_launch(void* const* d_in, const int* in_sizes, int n_in,
                              void* d_out, int out_size, void* d_ws, size_t ws_size,
                              hipStream_t stream) {
  const float* node_feat = (const float*)d_in[0];
  const int*   edge_idx  = (const int*)d_in[1];
  const float* edge_feat = (const float*)d_in[2];
  const float* W_edge    = (const float*)d_in[3];
  const float* b_edge    = (const float*)d_in[4];
  const float* W_ih      = (const float*)d_in[5];
  const float* W_hh      = (const float*)d_in[6];
  const float* b_ih      = (const float*)d_in[7];
  const float* b_hh      = (const float*)d_in[8];
  float* hF = (float*)d_out;

  char* p = (char*)d_ws;
  auto take = [&](size_t bytes) -> char* {
    char* r = p; p += (bytes + 255) & ~(size_t)255; return r;
  };
  ushort_t* WfT    = (ushort_t*)take(128*512*2);
  ushort_t* WihB   = (ushort_t*)take(384*128*2);
  ushort_t* WhhB   = (ushort_t*)take(384*128*2);
  int* cnt    = (int*)take((size_t)SCAN_N*4);
  int* off4   = (int*)take((size_t)(SCAN_N+1)*4);
  int* cursor = (int*)take((size_t)SCAN_N*4);
  int* bsum   = (int*)take((size_t)NB*4);
  int* bpre   = (int*)take((size_t)NB*4);
  int* packed = (int*)take((size_t)N_EDGES*4);
  int* sorted = (int*)take((size_t)N_EDGES*4);
  ushort_t* hB = (ushort_t*)take((size_t)N_NODES*128*2);
  ushort_t* sB = (ushort_t*)take((size_t)N_NODES*512*2);
  ushort_t* aB = (ushort_t*)take((size_t)N_NODES*128*2);

  hipMemsetAsync(cnt, 0, (size_t)SCAN_N*4, stream);

  prep_weights<<<640, 256, 0, stream>>>(W_edge, W_ih, W_hh, WfT, WihB, WhhB);
  edge_pass1<<<(N_EDGES+255)/256, 256, 0, stream>>>(edge_idx, edge_feat, packed, cnt);
  scan_pass1<<<NB, 256, 0, stream>>>(cnt, bsum);
  scan_pass2<<<1, 512, 0, stream>>>(bsum, bpre, off4 + SCAN_N, NB);
  scan_pass3<<<NB, 256, 0, stream>>>(cnt, bpre, off4, cursor);
  edge_place<<<(N_EDGES+255)/256, 256, 0, stream>>>(edge_idx, packed, cursor, sorted);
  init_h<<<(N_NODES*32 + 255)/256, 256, 0, stream>>>(node_feat, hF, hB, N_NODES*32);

  for (int step = 0; step < 4; ++step){
    agg_kernel<<<(N_NODES+3)/4, 256, 0, stream>>>(off4, sorted, hB, sB);
    gemm_a_kernel<<<(N_NODES+127)/128, 256, 0, stream>>>(sB, WfT, cnt, b_edge, aB);
    gru_kernel<<<(N_NODES+63)/64, 512, 0, stream>>>(aB, hB, WihB, WhhB, b_ih, b_hh, hF);
  }
}

// Round 3
// 961.048 us; speedup vs baseline: 1.9630x; 1.3047x over previous
//
#include <hip/hip_runtime.h>

#define N_NODES 100000
#define N_EDGES 1600000
#define HID 128
#define SCAN_N (N_NODES*4)
#define NB ((SCAN_N + 1023) / 1024)

typedef __attribute__((ext_vector_type(8))) short short8;
typedef __attribute__((ext_vector_type(4))) float float4v;
typedef __attribute__((ext_vector_type(4))) int int4v;
typedef __attribute__((ext_vector_type(2))) unsigned int uint2v;
typedef unsigned short ushort_t;
typedef unsigned int uint_t;

__device__ __forceinline__ float bits2f(uint_t u){ union{uint_t u; float f;} x; x.u=u; return x.f; }
__device__ __forceinline__ ushort_t f2b(float f){
  union{float f; uint_t u;} x; x.f=f;
  uint_t r = x.u + 0x7fffu + ((x.u>>16)&1u);
  return (ushort_t)(r>>16);
}
__device__ __forceinline__ float sigm(float x){ return 1.0f/(1.0f+__expf(-x)); }
__device__ __forceinline__ float tanh_f(float x){
  float t=__expf(-2.0f*fabsf(x)); float y=(1.0f-t)/(1.0f+t); return x>=0.f? y : -y;
}
__device__ __forceinline__ int imin(int a, int b){ return a < b ? a : b; }

// ---------------- preprocessing ----------------

// WfT[o][t*128+d] = W_edge[t][o][d]  (linear [128][512])
// W2[512][256]: permuted+zero-padded combined GRU weights (see gru_kernel)
__global__ void prep_weights(const float* __restrict__ W_edge, const float* __restrict__ W_ih,
                             const float* __restrict__ W_hh, ushort_t* __restrict__ WfT,
                             ushort_t* __restrict__ W2){
  int i = blockIdx.x*256 + threadIdx.x;
  if (i < 65536){
    int o = i >> 9, k = i & 511, t = k >> 7, d = k & 127;
    WfT[i] = f2b(W_edge[t*16384 + o*128 + d]);
  } else if (i < 65536 + 131072){
    int i2 = i - 65536;
    int n_l = i2 >> 8, k = i2 & 255;
    int wn = n_l >> 7, j = (n_l >> 4) & 7, rr = n_l & 15;
    int c = wn*32 + (j&1)*16 + rr;     // output column 0..127
    int jg = j >> 1;                   // 0:r 1:z 2:inn 3:hn
    float v;
    if (jg < 2)       v = (k < 128) ? W_ih[(jg*128 + c)*128 + k] : W_hh[(jg*128 + c)*128 + (k-128)];
    else if (jg == 2) v = (k < 128) ? W_ih[(256 + c)*128 + k] : 0.0f;
    else              v = (k >= 128) ? W_hh[(256 + c)*128 + (k-128)] : 0.0f;
    W2[n_l*256 + k] = f2b(v);
  }
}

// etype argmax, pack (t,src), histogram cnt[dst*4+t]
__global__ void edge_pass1(const int* __restrict__ eidx, const float* __restrict__ efeat,
                           int* __restrict__ packed, int* __restrict__ cnt){
  int e = blockIdx.x*256 + threadIdx.x;
  if (e >= N_EDGES) return;
  int src = eidx[e], dst = eidx[N_EDGES + e];
  float4v f = *(const float4v*)(efeat + (size_t)e*4);
  int t = 0; float b = f[0];
  if (f[1] > b){ b = f[1]; t = 1; }
  if (f[2] > b){ b = f[2]; t = 2; }
  if (f[3] > b){ b = f[3]; t = 3; }
  packed[e] = (t << 17) | src;
  atomicAdd(&cnt[dst*4 + t], 1);
}

// 3-pass exclusive scan over cnt[SCAN_N] -> off4, cursor copy
__global__ void scan_pass1(const int* __restrict__ cnt, int* __restrict__ bsum){
  __shared__ int ws[4];
  int tid = threadIdx.x, lane = tid & 63, w = tid >> 6;
  int idx = blockIdx.x*1024 + tid*4;
  int v = 0;
  if (idx + 3 < SCAN_N){ int4v x = *(const int4v*)(cnt + idx); v = x[0]+x[1]+x[2]+x[3]; }
  else { for (int k = 0; k < 4; ++k) if (idx + k < SCAN_N) v += cnt[idx+k]; }
  for (int d = 32; d; d >>= 1) v += __shfl_down(v, d);
  if (lane == 0) ws[w] = v;
  __syncthreads();
  if (tid == 0) bsum[blockIdx.x] = ws[0]+ws[1]+ws[2]+ws[3];
}

__global__ void scan_pass2(const int* __restrict__ bsum, int* __restrict__ bpre,
                           int* __restrict__ off4_last, int nb){
  __shared__ int sh[512];
  int tid = threadIdx.x;
  int v = (tid < nb) ? bsum[tid] : 0;
  sh[tid] = v;
  __syncthreads();
  for (int d = 1; d < 512; d <<= 1){
    int y = (tid >= d) ? sh[tid-d] : 0;
    __syncthreads();
    sh[tid] += y;
    __syncthreads();
  }
  if (tid < nb) bpre[tid] = sh[tid] - v;
  if (tid == 511) *off4_last = sh[511];
}

__global__ void scan_pass3(const int* __restrict__ cnt, const int* __restrict__ bpre,
                           int* __restrict__ off4, int* __restrict__ cur){
  __shared__ int wsum[4];
  int tid = threadIdx.x, lane = tid & 63, w = tid >> 6;
  int idx = blockIdx.x*1024 + tid*4;
  int v0=0,v1=0,v2=0,v3=0;
  if (idx + 3 < SCAN_N){ int4v x = *(const int4v*)(cnt + idx); v0=x[0];v1=x[1];v2=x[2];v3=x[3]; }
  else {
    if (idx   < SCAN_N) v0 = cnt[idx];
    if (idx+1 < SCAN_N) v1 = cnt[idx+1];
    if (idx+2 < SCAN_N) v2 = cnt[idx+2];
    if (idx+3 < SCAN_N) v3 = cnt[idx+3];
  }
  int ts = v0+v1+v2+v3;
  int sc = ts;
  for (int d = 1; d < 64; d <<= 1){ int y = __shfl_up(sc, d); if (lane >= d) sc += y; }
  if (lane == 63) wsum[w] = sc;
  __syncthreads();
  int wofs = 0;
  for (int k = 0; k < w; ++k) wofs += wsum[k];
  int base = bpre[blockIdx.x] + wofs + sc - ts;
  int e0 = base, e1 = e0+v0, e2 = e1+v1, e3 = e2+v2;
  if (idx   < SCAN_N){ off4[idx  ] = e0; cur[idx  ] = e0; }
  if (idx+1 < SCAN_N){ off4[idx+1] = e1; cur[idx+1] = e1; }
  if (idx+2 < SCAN_N){ off4[idx+2] = e2; cur[idx+2] = e2; }
  if (idx+3 < SCAN_N){ off4[idx+3] = e3; cur[idx+3] = e3; }
}

// scatter edges sorted by (dst, etype); keep type bits in payload
__global__ void edge_place(const int* __restrict__ eidx, const int* __restrict__ packed,
                           int* __restrict__ cur, int* __restrict__ sorted){
  int e = blockIdx.x*256 + threadIdx.x;
  if (e >= N_EDGES) return;
  int dst = eidx[N_EDGES + e];
  int p = packed[e];
  int t = p >> 17;
  int pos = atomicAdd(&cur[dst*4 + t], 1);
  sorted[pos] = p;
}

// h(f32)=node_feat (into d_out), h_bf16 copy
__global__ void init_h(const float* __restrict__ nf, float* __restrict__ hF,
                       ushort_t* __restrict__ hB, int n4){
  int i = blockIdx.x*256 + threadIdx.x;
  if (i >= n4) return;
  float4v v = *(const float4v*)(nf + (size_t)i*4);
  *(float4v*)(hF + (size_t)i*4) = v;
  uint2v u;
  u[0] = (uint_t)f2b(v[0]) | ((uint_t)f2b(v[1])<<16);
  u[1] = (uint_t)f2b(v[2]) | ((uint_t)f2b(v[3])<<16);
  *(uint2v*)(hB + (size_t)i*4) = u;
}

// ---------------- per-step kernels ----------------

#define ACCUM(hv, tt) { float f0_ = bits2f(((hv) & 0xffffu)<<16), f1_ = bits2f((hv) & 0xffff0000u); \
  if ((tt)==0){ r00+=f0_; r01+=f1_; } else if ((tt)==1){ r10+=f0_; r11+=f1_; } \
  else if ((tt)==2){ r20+=f0_; r21+=f1_; } else { r30+=f0_; r31+=f1_; } }

// one wave per node; unified edge loop, 8 independent gathers in flight
__global__ void agg_kernel(const int* __restrict__ off4, const int* __restrict__ sorted,
                           const ushort_t* __restrict__ hB, ushort_t* __restrict__ sB){
  int wid = (int)((blockIdx.x * blockDim.x + threadIdx.x) >> 6);
  int lane = threadIdx.x & 63;
  if (wid >= N_NODES) return;
  int s = off4[wid*4], e = off4[wid*4+4];
  int col = lane*2;
  float r00=0,r01=0,r10=0,r11=0,r20=0,r21=0,r30=0,r31=0;
  int i = s;
  for (; i + 8 <= e; i += 8){
    int p0 = __builtin_amdgcn_readfirstlane(sorted[i+0]);
    int p1 = __builtin_amdgcn_readfirstlane(sorted[i+1]);
    int p2 = __builtin_amdgcn_readfirstlane(sorted[i+2]);
    int p3 = __builtin_amdgcn_readfirstlane(sorted[i+3]);
    int p4 = __builtin_amdgcn_readfirstlane(sorted[i+4]);
    int p5 = __builtin_amdgcn_readfirstlane(sorted[i+5]);
    int p6 = __builtin_amdgcn_readfirstlane(sorted[i+6]);
    int p7 = __builtin_amdgcn_readfirstlane(sorted[i+7]);
    uint_t h0 = *(const uint_t*)(hB + (size_t)(p0 & 0x1FFFF)*128 + col);
    uint_t h1 = *(const uint_t*)(hB + (size_t)(p1 & 0x1FFFF)*128 + col);
    uint_t h2 = *(const uint_t*)(hB + (size_t)(p2 & 0x1FFFF)*128 + col);
    uint_t h3 = *(const uint_t*)(hB + (size_t)(p3 & 0x1FFFF)*128 + col);
    uint_t h4 = *(const uint_t*)(hB + (size_t)(p4 & 0x1FFFF)*128 + col);
    uint_t h5 = *(const uint_t*)(hB + (size_t)(p5 & 0x1FFFF)*128 + col);
    uint_t h6 = *(const uint_t*)(hB + (size_t)(p6 & 0x1FFFF)*128 + col);
    uint_t h7 = *(const uint_t*)(hB + (size_t)(p7 & 0x1FFFF)*128 + col);
    ACCUM(h0, p0>>17); ACCUM(h1, p1>>17); ACCUM(h2, p2>>17); ACCUM(h3, p3>>17);
    ACCUM(h4, p4>>17); ACCUM(h5, p5>>17); ACCUM(h6, p6>>17); ACCUM(h7, p7>>17);
  }
  if (i < e){
    // masked final chunk: clamped indices keep 8 loads in flight, tail dup loads are L1 hits
    int p0 = __builtin_amdgcn_readfirstlane(sorted[imin(i+0, e-1)]);
    int p1 = __builtin_amdgcn_readfirstlane(sorted[imin(i+1, e-1)]);
    int p2 = __builtin_amdgcn_readfirstlane(sorted[imin(i+2, e-1)]);
    int p3 = __builtin_amdgcn_readfirstlane(sorted[imin(i+3, e-1)]);
    int p4 = __builtin_amdgcn_readfirstlane(sorted[imin(i+4, e-1)]);
    int p5 = __builtin_amdgcn_readfirstlane(sorted[imin(i+5, e-1)]);
    int p6 = __builtin_amdgcn_readfirstlane(sorted[imin(i+6, e-1)]);
    int p7 = __builtin_amdgcn_readfirstlane(sorted[imin(i+7, e-1)]);
    uint_t h0 = *(const uint_t*)(hB + (size_t)(p0 & 0x1FFFF)*128 + col);
    uint_t h1 = *(const uint_t*)(hB + (size_t)(p1 & 0x1FFFF)*128 + col);
    uint_t h2 = *(const uint_t*)(hB + (size_t)(p2 & 0x1FFFF)*128 + col);
    uint_t h3 = *(const uint_t*)(hB + (size_t)(p3 & 0x1FFFF)*128 + col);
    uint_t h4 = *(const uint_t*)(hB + (size_t)(p4 & 0x1FFFF)*128 + col);
    uint_t h5 = *(const uint_t*)(hB + (size_t)(p5 & 0x1FFFF)*128 + col);
    uint_t h6 = *(const uint_t*)(hB + (size_t)(p6 & 0x1FFFF)*128 + col);
    uint_t h7 = *(const uint_t*)(hB + (size_t)(p7 & 0x1FFFF)*128 + col);
    ACCUM(h0, p0>>17);
    if (i+1 < e) ACCUM(h1, p1>>17);
    if (i+2 < e) ACCUM(h2, p2>>17);
    if (i+3 < e) ACCUM(h3, p3>>17);
    if (i+4 < e) ACCUM(h4, p4>>17);
    if (i+5 < e) ACCUM(h5, p5>>17);
    if (i+6 < e) ACCUM(h6, p6>>17);
    if (i+7 < e) ACCUM(h7, p7>>17);
  }
  size_t o = (size_t)wid*512 + (size_t)col;
  *(uint_t*)(sB + o + 0  ) = (uint_t)f2b(r00) | ((uint_t)f2b(r01)<<16);
  *(uint_t*)(sB + o + 128) = (uint_t)f2b(r10) | ((uint_t)f2b(r11)<<16);
  *(uint_t*)(sB + o + 256) = (uint_t)f2b(r20) | ((uint_t)f2b(r21)<<16);
  *(uint_t*)(sB + o + 384) = (uint_t)f2b(r30) | ((uint_t)f2b(r31)<<16);
}

// a_bf16 = s(Nx512) @ WfT^T(512x128) + sum_t cnt[v][t]*b_edge[t][:]
// LDS tiles [R][64] with XOR chunk swizzle: elem = r*64 + ((ch ^ (r&7))<<3)
__launch_bounds__(256)
__global__ void gemm_a_kernel(const ushort_t* __restrict__ sB, const ushort_t* __restrict__ WfT,
                              const int* __restrict__ cnt, const float* __restrict__ b_edge,
                              ushort_t* __restrict__ aB){
  __shared__ ushort_t lA[128*64];
  __shared__ ushort_t lB[128*64];
  int tid = threadIdx.x;
  int w = tid >> 6, lane = tid & 63;
  int wm = w >> 1, wn = w & 1;
  int row0 = blockIdx.x * 128;
  float4v acc[4][4] = {};
  for (int kt = 0; kt < 8; ++kt){
    int k0 = kt * 64;
    short8 va[4], vw[4];
    #pragma unroll
    for (int i = 0; i < 4; ++i){
      int cidx = i*256 + tid;
      int r = cidx >> 3, ch = cidx & 7;
      int grow = row0 + r; if (grow >= N_NODES) grow = N_NODES-1;
      va[i] = *reinterpret_cast<const short8*>(sB + (size_t)grow*512 + k0 + ch*8);
      vw[i] = *reinterpret_cast<const short8*>(WfT + r*512 + k0 + ch*8);
    }
    __syncthreads();
    #pragma unroll
    for (int i = 0; i < 4; ++i){
      int cidx = i*256 + tid;
      int r = cidx >> 3, ch = cidx & 7;
      *reinterpret_cast<short8*>(lA + r*64 + ((ch ^ (r&7))<<3)) = va[i];
      *reinterpret_cast<short8*>(lB + r*64 + ((ch ^ (r&7))<<3)) = vw[i];
    }
    __syncthreads();
    #pragma unroll
    for (int kk = 0; kk < 2; ++kk){
      int lch = kk*4 + (lane>>4);
      short8 af[4], bf[4];
      #pragma unroll
      for (int i = 0; i < 4; ++i){
        int r = wm*64 + i*16 + (lane&15);
        af[i] = *reinterpret_cast<const short8*>(lA + r*64 + ((lch ^ (r&7))<<3));
      }
      #pragma unroll
      for (int j = 0; j < 4; ++j){
        int rb = wn*64 + j*16 + (lane&15);
        bf[j] = *reinterpret_cast<const short8*>(lB + rb*64 + ((lch ^ (rb&7))<<3));
      }
      #pragma unroll
      for (int i = 0; i < 4; ++i)
        #pragma unroll
        for (int j = 0; j < 4; ++j)
          acc[i][j] = __builtin_amdgcn_mfma_f32_16x16x32_bf16(af[i], bf[j], acc[i][j], 0, 0, 0);
    }
  }
  #pragma unroll
  for (int i = 0; i < 4; ++i){
    #pragma unroll
    for (int q = 0; q < 4; ++q){
      int grow = row0 + wm*64 + i*16 + (lane>>4)*4 + q;
      if (grow >= N_NODES) continue;
      const int* c4 = cnt + grow*4;
      float c0 = (float)c4[0], c1 = (float)c4[1], c2 = (float)c4[2], c3 = (float)c4[3];
      #pragma unroll
      for (int j = 0; j < 4; ++j){
        int colc = wn*64 + j*16 + (lane&15);
        float v = acc[i][j][q] + c0*b_edge[colc] + c1*b_edge[128+colc]
                               + c2*b_edge[256+colc] + c3*b_edge[384+colc];
        aB[(size_t)grow*128 + colc] = f2b(v);
      }
    }
  }
}

// fused GRU as one GEMM: [a|h](128x256) @ W2^T(512x256), W2 rows permuted so wave wn's
// 8 N-tiles are {r,z,inn,hn} x {jj} for cols wn*32..wn*32+31; gate algebra in-register.
__launch_bounds__(512, 2)
__global__ void gru_kernel(const ushort_t* __restrict__ aB, ushort_t* __restrict__ hB,
                           const ushort_t* __restrict__ W2, const float* __restrict__ b_ih,
                           const float* __restrict__ b_hh, float* __restrict__ hF){
  __shared__ ushort_t lA[128*64];
  __shared__ ushort_t lB[512*64];
  int tid = threadIdx.x, w = tid >> 6, lane = tid & 63;
  int wm = w >> 2, wn = w & 3;
  int row0 = blockIdx.x * 128;
  float4v acc[4][8] = {};
  for (int kt = 0; kt < 4; ++kt){
    short8 va[2], vb[8];
    const ushort_t* srcA = (kt < 2) ? aB : hB;
    #pragma unroll
    for (int i = 0; i < 2; ++i){
      int cidx = i*512 + tid;
      int r = cidx >> 3, ch = cidx & 7;
      int node = row0 + r; if (node >= N_NODES) node = N_NODES-1;
      va[i] = *reinterpret_cast<const short8*>(srcA + (size_t)node*128 + (kt&1)*64 + ch*8);
    }
    #pragma unroll
    for (int i = 0; i < 8; ++i){
      int cidx = i*512 + tid;
      int n = cidx >> 3, ch = cidx & 7;
      vb[i] = *reinterpret_cast<const short8*>(W2 + (size_t)n*256 + kt*64 + ch*8);
    }
    __syncthreads();
    #pragma unroll
    for (int i = 0; i < 2; ++i){
      int cidx = i*512 + tid;
      int r = cidx >> 3, ch = cidx & 7;
      *reinterpret_cast<short8*>(lA + r*64 + ((ch ^ (r&7))<<3)) = va[i];
    }
    #pragma unroll
    for (int i = 0; i < 8; ++i){
      int cidx = i*512 + tid;
      int n = cidx >> 3, ch = cidx & 7;
      *reinterpret_cast<short8*>(lB + n*64 + ((ch ^ (n&7))<<3)) = vb[i];
    }
    __syncthreads();
    #pragma unroll
    for (int kk = 0; kk < 2; ++kk){
      int lch = kk*4 + (lane>>4);
      short8 af[4], bf[8];
      #pragma unroll
      for (int i = 0; i < 4; ++i){
        int r = wm*64 + i*16 + (lane&15);
        af[i] = *reinterpret_cast<const short8*>(lA + r*64 + ((lch ^ (r&7))<<3));
      }
      #pragma unroll
      for (int j = 0; j < 8; ++j){
        int n = wn*128 + j*16 + (lane&15);
        bf[j] = *reinterpret_cast<const short8*>(lB + n*64 + ((lch ^ (n&7))<<3));
      }
      #pragma unroll
      for (int i = 0; i < 4; ++i)
        #pragma unroll
        for (int j = 0; j < 8; ++j)
          acc[i][j] = __builtin_amdgcn_mfma_f32_16x16x32_bf16(af[i], bf[j], acc[i][j], 0, 0, 0);
    }
  }
  // epilogue: tiles j = {0,1}:r  {2,3}:z  {4,5}:inn  {6,7}:hn  (jj = j&1 -> col half)
  #pragma unroll
  for (int i = 0; i < 4; ++i){
    #pragma unroll
    for (int jj = 0; jj < 2; ++jj){
      int c = wn*32 + jj*16 + (lane&15);
      float br = b_ih[c] + b_hh[c];
      float bz = b_ih[128+c] + b_hh[128+c];
      float bni = b_ih[256+c], bnh = b_hh[256+c];
      #pragma unroll
      for (int q = 0; q < 4; ++q){
        int rrow = row0 + wm*64 + i*16 + (lane>>4)*4 + q;
        if (rrow >= N_NODES) continue;
        float rg = sigm(acc[i][0+jj][q] + br);
        float zg = sigm(acc[i][2+jj][q] + bz);
        float hn = acc[i][6+jj][q] + bnh;
        float nn = tanh_f(acc[i][4+jj][q] + bni + rg*hn);
        float h = hF[(size_t)rrow*128 + c];
        float out = (1.0f - zg)*nn + zg*h;
        hF[(size_t)rrow*128 + c] = out;
        hB[(size_t)rrow*128 + c] = f2b(out);
      }
    }
  }
}

// ---------------- launch ----------------

extern "C" void kernel_launch(void* const* d_in, const int* in_sizes, int n_in,
                              void* d_out, int out_size, void* d_ws, size_t ws_size,
                              hipStream_t stream) {
  const float* node_feat = (const float*)d_in[0];
  const int*   edge_idx  = (const int*)d_in[1];
  const float* edge_feat = (const float*)d_in[2];
  const float* W_edge    = (const float*)d_in[3];
  const float* b_edge    = (const float*)d_in[4];
  const float* W_ih      = (const float*)d_in[5];
  const float* W_hh      = (const float*)d_in[6];
  const float* b_ih      = (const float*)d_in[7];
  const float* b_hh      = (const float*)d_in[8];
  float* hF = (float*)d_out;

  char* p = (char*)d_ws;
  auto take = [&](size_t bytes) -> char* {
    char* r = p; p += (bytes + 255) & ~(size_t)255; return r;
  };
  ushort_t* WfT    = (ushort_t*)take(128*512*2);
  ushort_t* W2     = (ushort_t*)take(512*256*2);
  int* cnt    = (int*)take((size_t)SCAN_N*4);
  int* off4   = (int*)take((size_t)(SCAN_N+1)*4);
  int* cursor = (int*)take((size_t)SCAN_N*4);
  int* bsum   = (int*)take((size_t)NB*4);
  int* bpre   = (int*)take((size_t)NB*4);
  int* packed = (int*)take((size_t)N_EDGES*4);
  int* sorted = (int*)take((size_t)N_EDGES*4);
  ushort_t* hB = (ushort_t*)take((size_t)N_NODES*128*2);
  ushort_t* sB = (ushort_t*)take((size_t)N_NODES*512*2);
  ushort_t* aB = (ushort_t*)take((size_t)N_NODES*128*2);

  hipMemsetAsync(cnt, 0, (size_t)SCAN_N*4, stream);

  prep_weights<<<768, 256, 0, stream>>>(W_edge, W_ih, W_hh, WfT, W2);
  edge_pass1<<<(N_EDGES+255)/256, 256, 0, stream>>>(edge_idx, edge_feat, packed, cnt);
  scan_pass1<<<NB, 256, 0, stream>>>(cnt, bsum);
  scan_pass2<<<1, 512, 0, stream>>>(bsum, bpre, off4 + SCAN_N, NB);
  scan_pass3<<<NB, 256, 0, stream>>>(cnt, bpre, off4, cursor);
  edge_place<<<(N_EDGES+255)/256, 256, 0, stream>>>(edge_idx, packed, cursor, sorted);
  init_h<<<(N_NODES*32 + 255)/256, 256, 0, stream>>>(node_feat, hF, hB, N_NODES*32);

  int gemm_blocks = (N_NODES + 127) / 128;
  for (int step = 0; step < 4; ++step){
    agg_kernel<<<(N_NODES+3)/4, 256, 0, stream>>>(off4, sorted, hB, sB);
    gemm_a_kernel<<<gemm_blocks, 256, 0, stream>>>(sB, WfT, cnt, b_edge, aB);
    gru_kernel<<<gemm_blocks, 512, 0, stream>>>(aB, hB, W2, b_ih, b_hh, hF);
  }
}